// Round 4
// baseline (283.428 us; speedup 1.0000x reference)
//
#include <hip/hip_runtime.h>
#include <hip/hip_bf16.h>

// Embedding gather: out[token, :] = kernel[idx[token], :]
// TOKENS = 32*8192 = 262144, EMBED = 256, VOCAB = 256.
// Dtypes CONFIRMED by R2's on-device detector (error bit-identical to R1's
// f32/int32 path => detector selected it): indices int32, table f32.
// Output follows the reference dtype per the harness doc => FLOAT32.
// (R1's bf16-out theory was wrong: "(bf16" in the test label is hardcoded
// static text, not evidence of the readout branch taken.)
//
// Memory-bound: 256 MiB f32 written + 1 MiB idx read + 256 KiB table
// (L2-resident, reused ~1024x). Roofline ~41 us at 6.3 TB/s achievable.
// Layout: one wave64 per row; each lane moves one 16 B uint4 (4 f32) ->
// 1024 B fully-coalesced per wave. Block 256 = 4 rows. Index load is
// wave-uniform (same-address broadcast).

#define EMBED 256
#define ROWS_PER_BLOCK 4   // 256 threads / 64 threads-per-row

__global__ __launch_bounds__(256) void embedding_gather_kernel(
    const int* __restrict__ indices,          // [TOKENS] int32
    const uint4* __restrict__ table,          // [VOCAB*EMBED] f32 as 16B chunks
    uint4* __restrict__ out,                  // [TOKENS*EMBED] f32 as 16B chunks
    int tokens)
{
    const int t = threadIdx.x;
    const int row_local = t >> 6;             // 0..3
    const int chunk     = t & 63;             // 0..63 (16B chunks per 1KiB row)
    const int token = blockIdx.x * ROWS_PER_BLOCK + row_local;
    if (token >= tokens) return;

    const int idx = indices[token];           // wave-uniform broadcast

    // row = 256 f32 = 1024 B = 64 x uint4
    const uint4 v = table[(size_t)idx * (EMBED / 4) + chunk];
    out[(size_t)token * (EMBED / 4) + chunk] = v;
}

extern "C" void kernel_launch(void* const* d_in, const int* in_sizes, int n_in,
                              void* d_out, int out_size, void* d_ws, size_t ws_size,
                              hipStream_t stream) {
    const int*   indices = (const int*)d_in[0];   // [262144] int32
    const uint4* table   = (const uint4*)d_in[1]; // [256*256] f32 as 16B chunks
    uint4*       out     = (uint4*)d_out;         // [262144*256] f32 as 16B chunks

    const int tokens = in_sizes[0];               // 262144
    const int blocks = (tokens + ROWS_PER_BLOCK - 1) / ROWS_PER_BLOCK;  // 65536

    embedding_gather_kernel<<<blocks, 256, 0, stream>>>(indices, table, out, tokens);
}

// Round 5
// 255.390 us; speedup vs baseline: 1.1098x; 1.1098x over previous
//
#include <hip/hip_runtime.h>
#include <hip/hip_bf16.h>

// Embedding gather: out[token, :] = kernel[idx[token], :]  (all f32)
// TOKENS = 262144, EMBED = 256 (1 KiB/row), VOCAB = 256 (table 256 KiB,
// L2-resident). PASSED in R4 (absmax 0.0) with one-row-per-wave, one store
// per thread, 65536 workgroups -> ~118 us (2.9x the 41 us write roofline):
// block lifetime was ~3 memory ops, dispatch overhead + no store pipelining.
//
// R5: persistent waves. 1024 blocks x 256 thr = 4096 waves; each wave copies
// 64 consecutive rows (64 KiB contiguous writes). One coalesced batch load
// of 64 indices per wave, v_readlane broadcast per row, one uint4 per lane
// per row, unroll 4 for ILP (4 independent L2-hit loads + stores in flight).

#define EMBED 256
#define CHUNKS_PER_ROW (EMBED / 4)      // 64 x uint4 per 1 KiB row
#define ROWS_PER_WAVE 64
#define WAVES_PER_BLOCK 4

__global__ __launch_bounds__(256) void embedding_gather_kernel(
    const int* __restrict__ indices,          // [TOKENS] int32
    const uint4* __restrict__ table,          // [VOCAB*EMBED] f32 as 16B chunks
    uint4* __restrict__ out,                  // [TOKENS*EMBED] f32 as 16B chunks
    int tokens)
{
    const int lane    = threadIdx.x & 63;
    const int wave_id = blockIdx.x * WAVES_PER_BLOCK + (threadIdx.x >> 6);
    const int row_base = wave_id * ROWS_PER_WAVE;
    if (row_base >= tokens) return;

    // One coalesced load: lane l holds the index for row (row_base + l).
    int my_idx = 0;
    if (row_base + lane < tokens) my_idx = indices[row_base + lane];

    const int rows = (tokens - row_base < ROWS_PER_WAVE) ? (tokens - row_base)
                                                         : ROWS_PER_WAVE;

    #pragma unroll 4
    for (int i = 0; i < rows; ++i) {
        // Wave-uniform broadcast -> SGPR base for the table row.
        const int idx = __builtin_amdgcn_readlane(my_idx, i);
        const uint4 v = table[(size_t)idx * CHUNKS_PER_ROW + lane];
        out[((size_t)row_base + i) * CHUNKS_PER_ROW + lane] = v;
    }
}

extern "C" void kernel_launch(void* const* d_in, const int* in_sizes, int n_in,
                              void* d_out, int out_size, void* d_ws, size_t ws_size,
                              hipStream_t stream) {
    const int*   indices = (const int*)d_in[0];   // [262144] int32
    const uint4* table   = (const uint4*)d_in[1]; // [256*256] f32 as 16B chunks
    uint4*       out     = (uint4*)d_out;         // [262144*256] f32 as 16B chunks

    const int tokens = in_sizes[0];               // 262144
    const int waves  = (tokens + ROWS_PER_WAVE - 1) / ROWS_PER_WAVE;   // 4096
    const int blocks = (waves + WAVES_PER_BLOCK - 1) / WAVES_PER_BLOCK; // 1024

    embedding_gather_kernel<<<blocks, 256, 0, stream>>>(indices, table, out, tokens);
}